// Round 4
// baseline (475.477 us; speedup 1.0000x reference)
//
#include <hip/hip_runtime.h>

#define NFEAT 64

// ---------------- prep: zero count; block 0 also detects int64 encoding ----
// Values < 50000 (17 bits): under int64 encoding every odd int32 word is 0.
__global__ void k_prep(const int* __restrict__ ei, int* __restrict__ flag,
                       int* __restrict__ count, int N) {
    int i = blockIdx.x * blockDim.x + threadIdx.x;
    if (i < N) count[i] = 0;
    if (blockIdx.x == 0) {
        __shared__ int any_nonzero;
        if (threadIdx.x == 0) any_nonzero = 0;
        __syncthreads();
        if (ei[2 * threadIdx.x + 1] != 0) atomicOr(&any_nonzero, 1);
        __syncthreads();
        if (threadIdx.x == 0) flag[0] = any_nonzero ? 0 : 1;   // 1 => int64
    }
}

__device__ __forceinline__ int load_idx(const int* __restrict__ ei, long long elem, int is64) {
    return is64 ? ei[2 * elem] : ei[(int)elem];
}

// ---------------- histogram of dst (real edges only) ------------------------
__global__ void k_hist(const int* __restrict__ ei, const int* __restrict__ flag,
                       int* __restrict__ count, int E) {
    int i = blockIdx.x * blockDim.x + threadIdx.x;
    if (i >= E) return;
    int is64 = flag[0];
    int d = load_idx(ei, (long long)E + i, is64);
    atomicAdd(&count[d], 1);
}

// ------- deg-derived per-node factors + y = dinv * x (one float4/thread) ----
__global__ void k_finalize(const int* __restrict__ count, const float* __restrict__ x,
                           float* __restrict__ dinv, float* __restrict__ scale,
                           float* __restrict__ y, int N) {
    int t = blockIdx.x * blockDim.x + threadIdx.x;   // over N*16 float4s
    if (t >= N * 16) return;
    int v = t >> 4;
    float dg = (float)(count[v] + 1);                // +1 self loop
    float dv = rsqrtf(dg);
    if ((t & 15) == 0) {
        dinv[v] = dv;
        scale[v] = dv / dg;                          // dinv[v]/deg[v]
    }
    float4 xv = ((const float4*)x)[t];
    float4 o;
    o.x = xv.x * dv; o.y = xv.y * dv; o.z = xv.z * dv; o.w = xv.w * dv;
    ((float4*)y)[t] = o;
}

// ---------------- scan stage 1: per-block sums of count ---------------------
__global__ void k_bsum(const int* __restrict__ count, int* __restrict__ bsum, int N) {
    __shared__ int s[256];
    int i = blockIdx.x * 256 + threadIdx.x;
    s[threadIdx.x] = (i < N) ? count[i] : 0;
    __syncthreads();
    for (int off = 128; off > 0; off >>= 1) {
        if (threadIdx.x < off) s[threadIdx.x] += s[threadIdx.x + off];
        __syncthreads();
    }
    if (threadIdx.x == 0) bsum[blockIdx.x] = s[0];
}

// ---------------- scan stage 2: exclusive scan of block sums (single block) --
__global__ void k_bscan(const int* __restrict__ bsum, int* __restrict__ bpre, int NB) {
    __shared__ int s[1024];
    int t = threadIdx.x;
    int mine = (t < NB) ? bsum[t] : 0;
    s[t] = mine;
    __syncthreads();
    for (int off = 1; off < 1024; off <<= 1) {
        int v = (t >= off) ? s[t - off] : 0;
        __syncthreads();
        s[t] += v;
        __syncthreads();
    }
    if (t < NB) bpre[t] = s[t] - mine;   // exclusive prefix
}

// ---------------- scan stage 3: ptr/fill = global exclusive scan ------------
__global__ void k_ptr(const int* __restrict__ count, const int* __restrict__ bpre,
                      int* __restrict__ ptr, int* __restrict__ fill, int N) {
    __shared__ int s[256];
    int i = blockIdx.x * 256 + threadIdx.x;
    int c = (i < N) ? count[i] : 0;
    s[threadIdx.x] = c;
    __syncthreads();
    for (int off = 1; off < 256; off <<= 1) {
        int v = (threadIdx.x >= off) ? s[threadIdx.x - off] : 0;
        __syncthreads();
        s[threadIdx.x] += v;
        __syncthreads();
    }
    if (i < N) {
        int excl = bpre[blockIdx.x] + s[threadIdx.x] - c;
        ptr[i] = excl;
        fill[i] = excl;
    }
}

// ---------------- fill CSR: sorted_src[pos] = src ----------------------------
__global__ void k_fill(const int* __restrict__ ei, const int* __restrict__ flag,
                       int* __restrict__ fill, int* __restrict__ sorted_src, int E) {
    int i = blockIdx.x * blockDim.x + threadIdx.x;
    if (i >= E) return;
    int is64 = flag[0];
    int s = load_idx(ei, i, is64);
    int d = load_idx(ei, (long long)E + i, is64);
    int pos = atomicAdd(&fill[d], 1);
    sorted_src[pos] = s;
}

// ---------------- gather (8 independent chains) + fused dual-GEMM epilogue ---
// Persistent-style grid: W1/W2 LDS fill amortized over ~10 nodes per wave.
__global__ __launch_bounds__(256, 4) void k_gather_out(
        const float* __restrict__ y, const float* __restrict__ scale,
        const int* __restrict__ ptr, const int* __restrict__ count,
        const int* __restrict__ sorted_src,
        const float* __restrict__ W1, const float* __restrict__ W2,
        float* __restrict__ out, int N) {
    __shared__ float w1[NFEAT * NFEAT];
    __shared__ float w2[NFEAT * NFEAT];
    for (int i = threadIdx.x; i < NFEAT * NFEAT; i += 256) {
        w1[i] = W1[i];
        w2[i] = W2[i];
    }
    __syncthreads();
    int wave = threadIdx.x >> 6;
    int lane = threadIdx.x & 63;

    for (int v = blockIdx.x * 4 + wave; v < N; v += gridDim.x * 4) {
        int start = ptr[v];
        int cnt = count[v];
        float sc = scale[v];
        // self-loop term: y[v] = dinv[v]*x[v]
        float a0 = y[(size_t)v * NFEAT + lane];
        float a1 = 0.f, a2 = 0.f, a3 = 0.f, a4 = 0.f, a5 = 0.f, a6 = 0.f, a7 = 0.f;

        for (int c = 0; c < cnt; c += 64) {
            int m = min(64, cnt - c);
            int s_l = 0;
            if (lane < m) s_l = sorted_src[start + c + lane];
            int j = 0;
            for (; j + 8 <= m; j += 8) {
                int s0 = __shfl(s_l, j + 0, 64), s1 = __shfl(s_l, j + 1, 64);
                int s2 = __shfl(s_l, j + 2, 64), s3 = __shfl(s_l, j + 3, 64);
                int s4 = __shfl(s_l, j + 4, 64), s5 = __shfl(s_l, j + 5, 64);
                int s6 = __shfl(s_l, j + 6, 64), s7 = __shfl(s_l, j + 7, 64);
                a0 += y[(size_t)s0 * NFEAT + lane];
                a1 += y[(size_t)s1 * NFEAT + lane];
                a2 += y[(size_t)s2 * NFEAT + lane];
                a3 += y[(size_t)s3 * NFEAT + lane];
                a4 += y[(size_t)s4 * NFEAT + lane];
                a5 += y[(size_t)s5 * NFEAT + lane];
                a6 += y[(size_t)s6 * NFEAT + lane];
                a7 += y[(size_t)s7 * NFEAT + lane];
            }
            for (; j < m; ++j) {
                int s0 = __shfl(s_l, j, 64);
                a0 += y[(size_t)s0 * NFEAT + lane];
            }
        }
        float a = ((a0 + a1) + (a2 + a3)) + ((a4 + a5) + (a6 + a7));
        a *= sc;   // * dinv[v] / deg[v]

        // dual GEMM: row 'a' (one element per lane) against W1/W2
        float acc1 = 0.0f, acc2 = 0.0f;
#pragma unroll
        for (int k = 0; k < NFEAT; ++k) {
            float ak = __shfl(a, k, 64);
            acc1 = fmaf(ak, w1[k * NFEAT + lane], acc1);
            acc2 = fmaf(ak, w2[k * NFEAT + lane], acc2);
        }
        float x1 = fmaxf(acc1, 0.0f);
        float x2 = 1.0f / (1.0f + __expf(-acc2));
        out[(size_t)v * NFEAT + lane] = x1 * x2;
    }
}

extern "C" void kernel_launch(void* const* d_in, const int* in_sizes, int n_in,
                              void* d_out, int out_size, void* d_ws, size_t ws_size,
                              hipStream_t stream) {
    const float* x  = (const float*)d_in[0];
    const int*   ei = (const int*)d_in[1];
    const float* W1 = (const float*)d_in[2];
    const float* W2 = (const float*)d_in[3];
    float* out = (float*)d_out;

    const int N = in_sizes[0] / NFEAT;       // 50000
    const int E = in_sizes[1] / 2;           // 1,600,000
    const int NB = (N + 255) / 256;          // scan blocks

    // workspace layout (256B-aligned slices)
    char* ws = (char*)d_ws;
    size_t off = 0;
    auto alloc = [&](size_t bytes) {
        char* p = ws + off;
        off = (off + bytes + 255) & ~(size_t)255;
        return p;
    };
    int*   flag       = (int*)alloc(256);
    int*   count      = (int*)alloc((size_t)N * 4);
    float* dinv       = (float*)alloc((size_t)N * 4);
    float* scale      = (float*)alloc((size_t)N * 4);
    int*   ptr        = (int*)alloc((size_t)N * 4);
    int*   fill       = (int*)alloc((size_t)N * 4);
    int*   bsum       = (int*)alloc((size_t)NB * 4);
    int*   bpre       = (int*)alloc((size_t)NB * 4);
    int*   sorted_src = (int*)alloc((size_t)E * 4);
    float* y          = (float*)alloc((size_t)N * NFEAT * 4);

    k_prep<<<NB, 256, 0, stream>>>(ei, flag, count, N);
    k_hist<<<(E + 255) / 256, 256, 0, stream>>>(ei, flag, count, E);
    k_finalize<<<(N * 16 + 255) / 256, 256, 0, stream>>>(count, x, dinv, scale, y, N);
    k_bsum<<<NB, 256, 0, stream>>>(count, bsum, N);
    k_bscan<<<1, 1024, 0, stream>>>(bsum, bpre, NB);
    k_ptr<<<NB, 256, 0, stream>>>(count, bpre, ptr, fill, N);
    k_fill<<<(E + 255) / 256, 256, 0, stream>>>(ei, flag, fill, sorted_src, E);

    int gblocks = 1280;                       // 5 blocks/CU * 256 CUs
    if (gblocks > (N + 3) / 4) gblocks = (N + 3) / 4;
    k_gather_out<<<gblocks, 256, 0, stream>>>(y, scale, ptr, count,
                                              sorted_src, W1, W2, out, N);
}

// Round 5
// 312.902 us; speedup vs baseline: 1.5196x; 1.5196x over previous
//
#include <hip/hip_runtime.h>

#define NFEAT 64

// ---------------- prep: zero count; block 0 also detects int64 encoding ----
// Values < 50000 (17 bits): under int64 encoding every odd int32 word is 0.
__global__ void k_prep(const int* __restrict__ ei, int* __restrict__ flag,
                       int* __restrict__ count, int N) {
    int i = blockIdx.x * blockDim.x + threadIdx.x;
    if (i < N) count[i] = 0;
    if (blockIdx.x == 0) {
        __shared__ int any_nonzero;
        if (threadIdx.x == 0) any_nonzero = 0;
        __syncthreads();
        if (ei[2 * threadIdx.x + 1] != 0) atomicOr(&any_nonzero, 1);
        __syncthreads();
        if (threadIdx.x == 0) flag[0] = any_nonzero ? 0 : 1;   // 1 => int64
    }
}

__device__ __forceinline__ int load_idx(const int* __restrict__ ei, long long elem, int is64) {
    return is64 ? ei[2 * elem] : ei[(int)elem];
}

// ---------------- histogram of dst (real edges only) ------------------------
__global__ void k_hist(const int* __restrict__ ei, const int* __restrict__ flag,
                       int* __restrict__ count, int E) {
    int i = blockIdx.x * blockDim.x + threadIdx.x;
    if (i >= E) return;
    int is64 = flag[0];
    int d = load_idx(ei, (long long)E + i, is64);
    atomicAdd(&count[d], 1);
}

// ------- per-node factors + y = dinv * x (one float4/thread) ----------------
__global__ void k_finalize(const int* __restrict__ count, const float* __restrict__ x,
                           float* __restrict__ scale, float* __restrict__ y, int N) {
    int t = blockIdx.x * blockDim.x + threadIdx.x;   // over N*16 float4s
    if (t >= N * 16) return;
    int v = t >> 4;
    float dg = (float)(count[v] + 1);                // +1 self loop
    float dv = rsqrtf(dg);
    if ((t & 15) == 0) scale[v] = dv / dg;           // dinv[v]/deg[v]
    float4 xv = ((const float4*)x)[t];
    float4 o;
    o.x = xv.x * dv; o.y = xv.y * dv; o.z = xv.z * dv; o.w = xv.w * dv;
    ((float4*)y)[t] = o;
}

// ---------------- scan stage 1: per-block sums of count ---------------------
__global__ void k_bsum(const int* __restrict__ count, int* __restrict__ bsum, int N) {
    __shared__ int s[256];
    int i = blockIdx.x * 256 + threadIdx.x;
    s[threadIdx.x] = (i < N) ? count[i] : 0;
    __syncthreads();
    for (int off = 128; off > 0; off >>= 1) {
        if (threadIdx.x < off) s[threadIdx.x] += s[threadIdx.x + off];
        __syncthreads();
    }
    if (threadIdx.x == 0) bsum[blockIdx.x] = s[0];
}

// ---------------- scan stage 2: exclusive scan of block sums (single block) --
__global__ void k_bscan(const int* __restrict__ bsum, int* __restrict__ bpre, int NB) {
    __shared__ int s[1024];
    int t = threadIdx.x;
    int mine = (t < NB) ? bsum[t] : 0;
    s[t] = mine;
    __syncthreads();
    for (int off = 1; off < 1024; off <<= 1) {
        int v = (t >= off) ? s[t - off] : 0;
        __syncthreads();
        s[t] += v;
        __syncthreads();
    }
    if (t < NB) bpre[t] = s[t] - mine;   // exclusive prefix
}

// ---------------- scan stage 3: ptr/fill = global exclusive scan ------------
__global__ void k_ptr(const int* __restrict__ count, const int* __restrict__ bpre,
                      int* __restrict__ ptr, int* __restrict__ fill, int N) {
    __shared__ int s[256];
    int i = blockIdx.x * 256 + threadIdx.x;
    int c = (i < N) ? count[i] : 0;
    s[threadIdx.x] = c;
    __syncthreads();
    for (int off = 1; off < 256; off <<= 1) {
        int v = (threadIdx.x >= off) ? s[threadIdx.x - off] : 0;
        __syncthreads();
        s[threadIdx.x] += v;
        __syncthreads();
    }
    if (i < N) {
        int excl = bpre[blockIdx.x] + s[threadIdx.x] - c;
        ptr[i] = excl;
        fill[i] = excl;
    }
}

// ---------------- fill CSR: sorted_src[pos] = src ----------------------------
__global__ void k_fill(const int* __restrict__ ei, const int* __restrict__ flag,
                       int* __restrict__ fill, int* __restrict__ sorted_src, int E) {
    int i = blockIdx.x * blockDim.x + threadIdx.x;
    if (i >= E) return;
    int is64 = flag[0];
    int s = load_idx(ei, i, is64);
    int d = load_idx(ei, (long long)E + i, is64);
    int pos = atomicAdd(&fill[d], 1);
    sorted_src[pos] = s;
}

// ---------------- gather only: agg_out[v] = scale[v] * (y[v] + sum y[src]) ---
// No LDS, no W. 4 waves/block, 4 consecutive nodes per wave (consecutive
// sweep — R4's grid-stride order thrashed L2). 8 independent gather chains.
__global__ __launch_bounds__(256) void k_gather(
        const float* __restrict__ y, const float* __restrict__ scale,
        const int* __restrict__ ptr, const int* __restrict__ count,
        const int* __restrict__ sorted_src, float* __restrict__ agg_out, int N) {
    int wave = threadIdx.x >> 6;
    int lane = threadIdx.x & 63;
    int vbase = blockIdx.x * 16 + wave * 4;

    for (int vi = 0; vi < 4; ++vi) {
        int v = vbase + vi;
        if (v >= N) return;
        int start = ptr[v];
        int cnt = count[v];
        float sc = scale[v];
        float a0 = y[(size_t)v * NFEAT + lane];   // self-loop term
        float a1 = 0.f, a2 = 0.f, a3 = 0.f, a4 = 0.f, a5 = 0.f, a6 = 0.f, a7 = 0.f;

        for (int c = 0; c < cnt; c += 64) {
            int m = min(64, cnt - c);
            int s_l = 0;
            if (lane < m) s_l = sorted_src[start + c + lane];
            int j = 0;
            for (; j + 8 <= m; j += 8) {
                int s0 = __shfl(s_l, j + 0, 64), s1 = __shfl(s_l, j + 1, 64);
                int s2 = __shfl(s_l, j + 2, 64), s3 = __shfl(s_l, j + 3, 64);
                int s4 = __shfl(s_l, j + 4, 64), s5 = __shfl(s_l, j + 5, 64);
                int s6 = __shfl(s_l, j + 6, 64), s7 = __shfl(s_l, j + 7, 64);
                a0 += y[(size_t)s0 * NFEAT + lane];
                a1 += y[(size_t)s1 * NFEAT + lane];
                a2 += y[(size_t)s2 * NFEAT + lane];
                a3 += y[(size_t)s3 * NFEAT + lane];
                a4 += y[(size_t)s4 * NFEAT + lane];
                a5 += y[(size_t)s5 * NFEAT + lane];
                a6 += y[(size_t)s6 * NFEAT + lane];
                a7 += y[(size_t)s7 * NFEAT + lane];
            }
            for (; j < m; ++j) {
                int s0 = __shfl(s_l, j, 64);
                a0 += y[(size_t)s0 * NFEAT + lane];
            }
        }
        float a = ((a0 + a1) + (a2 + a3)) + ((a4 + a5) + (a6 + a7));
        agg_out[(size_t)v * NFEAT + lane] = a * sc;
    }
}

// ---------------- epilogue: out[v] = relu(a@W1) * sigmoid(a@W2), in place ----
__global__ __launch_bounds__(256) void k_epi(
        float* __restrict__ io, const float* __restrict__ W1,
        const float* __restrict__ W2, int N) {
    __shared__ float w1[NFEAT * NFEAT];
    __shared__ float w2[NFEAT * NFEAT];
    for (int i = threadIdx.x; i < NFEAT * NFEAT; i += 256) {
        w1[i] = W1[i];
        w2[i] = W2[i];
    }
    __syncthreads();
    int wave = threadIdx.x >> 6;
    int lane = threadIdx.x & 63;
    for (int v = blockIdx.x * 4 + wave; v < N; v += gridDim.x * 4) {
        float a = io[(size_t)v * NFEAT + lane];
        float acc1 = 0.0f, acc2 = 0.0f;
#pragma unroll
        for (int k = 0; k < NFEAT; ++k) {
            float ak = __shfl(a, k, 64);
            acc1 = fmaf(ak, w1[k * NFEAT + lane], acc1);
            acc2 = fmaf(ak, w2[k * NFEAT + lane], acc2);
        }
        float x1 = fmaxf(acc1, 0.0f);
        float x2 = 1.0f / (1.0f + __expf(-acc2));
        io[(size_t)v * NFEAT + lane] = x1 * x2;
    }
}

extern "C" void kernel_launch(void* const* d_in, const int* in_sizes, int n_in,
                              void* d_out, int out_size, void* d_ws, size_t ws_size,
                              hipStream_t stream) {
    const float* x  = (const float*)d_in[0];
    const int*   ei = (const int*)d_in[1];
    const float* W1 = (const float*)d_in[2];
    const float* W2 = (const float*)d_in[3];
    float* out = (float*)d_out;

    const int N = in_sizes[0] / NFEAT;       // 50000
    const int E = in_sizes[1] / 2;           // 1,600,000
    const int NB = (N + 255) / 256;          // scan blocks

    // workspace layout (256B-aligned slices)
    char* ws = (char*)d_ws;
    size_t off = 0;
    auto alloc = [&](size_t bytes) {
        char* p = ws + off;
        off = (off + bytes + 255) & ~(size_t)255;
        return p;
    };
    int*   flag       = (int*)alloc(256);
    int*   count      = (int*)alloc((size_t)N * 4);
    float* scale      = (float*)alloc((size_t)N * 4);
    int*   ptr        = (int*)alloc((size_t)N * 4);
    int*   fill       = (int*)alloc((size_t)N * 4);
    int*   bsum       = (int*)alloc((size_t)NB * 4);
    int*   bpre       = (int*)alloc((size_t)NB * 4);
    int*   sorted_src = (int*)alloc((size_t)E * 4);
    float* y          = (float*)alloc((size_t)N * NFEAT * 4);

    k_prep<<<NB, 256, 0, stream>>>(ei, flag, count, N);
    k_hist<<<(E + 255) / 256, 256, 0, stream>>>(ei, flag, count, E);
    k_finalize<<<(N * 16 + 255) / 256, 256, 0, stream>>>(count, x, scale, y, N);
    k_bsum<<<NB, 256, 0, stream>>>(count, bsum, N);
    k_bscan<<<1, 1024, 0, stream>>>(bsum, bpre, NB);
    k_ptr<<<NB, 256, 0, stream>>>(count, bpre, ptr, fill, N);
    k_fill<<<(E + 255) / 256, 256, 0, stream>>>(ei, flag, fill, sorted_src, E);

    // gather writes scaled aggregation rows into d_out (scratch), epilogue
    // rewrites d_out in place.
    k_gather<<<(N + 15) / 16, 256, 0, stream>>>(y, scale, ptr, count,
                                                sorted_src, out, N);
    k_epi<<<512, 256, 0, stream>>>(out, W1, W2, N);
}